// Round 2
// baseline (1289.742 us; speedup 1.0000x reference)
//
#include <hip/hip_runtime.h>
#include <math.h>

// Problem constants
// N=64, C=64 (=Cout), T=256, V=25, S=3, inter=16
// x: [N,C,T,V] fp32;  out: [N,C,T,V] fp32

// ---------------------------------------------------------------------------
// Kernel A: fused embeddings + A1 Gram accumulation.
// grid = (s, n, tc) = 3*64*4 = 768 blocks, 256 threads.
// Each block covers 64 t-values (tc chunk), processed 4 t at a time.
// Accumulates P[s][n][v][w] = sum_{i,t} a[i,t,v]*b[i,t,w] via atomics.
// ---------------------------------------------------------------------------
__global__ __launch_bounds__(256) void gcn_kA(const float* __restrict__ x,
                                              const float* __restrict__ Wa,
                                              const float* __restrict__ ba,
                                              const float* __restrict__ Wb,
                                              const float* __restrict__ bb,
                                              float* __restrict__ Praw) {
    const int bid = blockIdx.x;
    const int tc = bid & 3;
    const int n  = (bid >> 2) & 63;
    const int s  = bid >> 8;
    const int tid = threadIdx.x;

    __shared__ float xs[6400];          // x[n][c][t0..t0+3][v]  (c*100 + r)
    __shared__ float aL[1600], bL[1600];// [i*100 + r] == [(i*4+t4)*25 + v]
    __shared__ float WaL[1024], WbL[1024];
    __shared__ float baL[16], bbL[16];

    for (int j = tid; j < 1024; j += 256) {
        WaL[j] = Wa[s * 1024 + j];
        WbL[j] = Wb[s * 1024 + j];
    }
    if (tid < 16) { baL[tid] = ba[s * 16 + tid]; bbL[tid] = bb[s * 16 + tid]; }

    float P0 = 0.f, P1 = 0.f, P2 = 0.f;
    const int p0 = tid, p1 = tid + 256, p2 = tid + 512;
    const int v0 = (int)(((unsigned long long)p0 * 1374389535ull) >> 35);
    const int w0 = p0 - v0 * 25;
    const int v1 = (int)(((unsigned long long)p1 * 1374389535ull) >> 35);
    const int w1 = p1 - v1 * 25;
    const int v2 = (int)(((unsigned long long)p2 * 1374389535ull) >> 35);
    const int w2 = p2 - v2 * 25;

    const int t0base = tc * 64;
    for (int tg = 0; tg < 16; ++tg) {
        const int t0 = t0base + tg * 4;
        __syncthreads();  // weights visible (iter 0) / prev Gram-read done
        // stage xs: 64 rows of 100 contiguous floats
        for (int j = tid; j < 6400; j += 256) {
            int c = (int)(((unsigned long long)j * 1374389535ull) >> 37); // j/100
            int r = j - c * 100;
            xs[j] = x[((n * 64 + c) * 256 + t0) * 25 + r];
        }
        __syncthreads();
        // embeddings a,b for this 4-t group
        for (int e = tid; e < 1600; e += 256) {
            int i = (int)(((unsigned long long)e * 1374389535ull) >> 37); // e/100
            int r = e - i * 100;
            float av = baL[i], bv = bbL[i];
            #pragma unroll 16
            for (int c = 0; c < 64; ++c) {
                float xv = xs[c * 100 + r];
                av += WaL[i * 64 + c] * xv;
                bv += WbL[i * 64 + c] * xv;
            }
            aL[e] = av; bL[e] = bv;
        }
        __syncthreads();
        // Gram accumulate: P[v][w] += sum_m a[m*25+v]*b[m*25+w], m = (i,t4)
        if (p0 < 625) {
            float acc = 0.f;
            #pragma unroll 16
            for (int m = 0; m < 64; ++m) acc += aL[m * 25 + v0] * bL[m * 25 + w0];
            P0 += acc;
        }
        if (p1 < 625) {
            float acc = 0.f;
            #pragma unroll 16
            for (int m = 0; m < 64; ++m) acc += aL[m * 25 + v1] * bL[m * 25 + w1];
            P1 += acc;
        }
        if (p2 < 625) {
            float acc = 0.f;
            #pragma unroll 16
            for (int m = 0; m < 64; ++m) acc += aL[m * 25 + v2] * bL[m * 25 + w2];
            P2 += acc;
        }
    }
    float* Pbase = Praw + (s * 64 + n) * 625;
    if (p0 < 625) atomicAdd(&Pbase[p0], P0);
    if (p1 < 625) atomicAdd(&Pbase[p1], P1);
    if (p2 < 625) atomicAdd(&Pbase[p2], P2);
}

// ---------------------------------------------------------------------------
// Kernel B: Ai = PA + alpha * tanh(P/4096).  120,000 elements.
// ---------------------------------------------------------------------------
__global__ __launch_bounds__(256) void gcn_kB(const float* __restrict__ Praw,
                                              const float* __restrict__ PA,
                                              const float* __restrict__ alpha,
                                              float* __restrict__ Ai) {
    int idx = blockIdx.x * 256 + threadIdx.x;
    if (idx >= 120000) return;
    int sn = idx / 625;
    int r  = idx - sn * 625;
    int s  = sn >> 6;
    Ai[idx] = PA[s * 625 + r] + alpha[0] * tanhf(Praw[idx] * (1.f / 4096.f));
}

// ---------------------------------------------------------------------------
// Kernel T: transpose Wd -> WdT[s][c][o].  12,288 elements.
// ---------------------------------------------------------------------------
__global__ __launch_bounds__(256) void gcn_kT(const float* __restrict__ Wd,
                                              float* __restrict__ WdT) {
    int idx = blockIdx.x * 256 + threadIdx.x;  // grid 48*256 == 12288
    int s = idx >> 12;
    int rem = idx & 4095;
    int c = rem >> 6;
    int o = rem & 63;
    WdT[idx] = Wd[s * 4096 + o * 64 + c];
}

// ---------------------------------------------------------------------------
// Kernel C: main graph conv:  y1 = relu(BN(sum_s Wd[s] @ (x @ Ai[s,n])) + x)
// grid = (n, tg) = 64*64 blocks, 256 threads = 64 (c|o) x 4 t'.
// Also accumulates sum-over-T of y1 into meanT[n][c][v] (atomics).
// ---------------------------------------------------------------------------
__global__ __launch_bounds__(256) void gcn_kC(const float* __restrict__ x,
                                              const float* __restrict__ Ai,
                                              const float* __restrict__ WdT,
                                              const float* __restrict__ bd,
                                              const float* __restrict__ gamma,
                                              const float* __restrict__ beta,
                                              float* __restrict__ y1,
                                              float* __restrict__ meanT) {
    const int bid = blockIdx.x;
    const int tg = bid & 63;
    const int n  = bid >> 6;
    const int tid = threadIdx.x;
    const int co = tid >> 2;     // c in stage1, o in stage2 (same thread)
    const int tp = tid & 3;      // t' within the 4-t group
    const int t  = tg * 4 + tp;

    __shared__ float AiL[3 * 700];       // padded rows: [s][v*28 + w]
    __shared__ float WdL[4096];          // WdT[s][c][o], one s at a time
    __shared__ float pL[64 * 112];       // [c][t'*28 + w] padded

    for (int j = tid; j < 1875; j += 256) {
        int s = j / 625;
        int r = j - s * 625;
        int v = r / 25;
        int w = r - v * 25;
        AiL[s * 700 + v * 28 + w] = Ai[(s * 64 + n) * 625 + r];
    }

    float xr[25];
    const float* xp = x + (size_t)((n * 64 + co) * 256 + t) * 25;
    #pragma unroll
    for (int v = 0; v < 25; ++v) xr[v] = xp[v];

    float acc[25];
    #pragma unroll
    for (int w = 0; w < 25; ++w) acc[w] = 0.f;

    for (int s = 0; s < 3; ++s) {
        __syncthreads();  // AiL ready (s=0) / prev stage2 fully consumed pL+WdL
        for (int j = tid; j < 4096; j += 256) WdL[j] = WdT[s * 4096 + j];
        // stage1: p[co][tp][w] = sum_v xr[v] * Ai[s][v][w]
        float pr[25];
        #pragma unroll
        for (int w = 0; w < 25; ++w) pr[w] = 0.f;
        const float* aiB = &AiL[s * 700];
        #pragma unroll
        for (int v = 0; v < 25; ++v) {
            float xv = xr[v];
            #pragma unroll
            for (int w = 0; w < 25; ++w) pr[w] += xv * aiB[v * 28 + w];
        }
        {
            float* pRow = &pL[co * 112 + tp * 28];
            #pragma unroll
            for (int w = 0; w < 25; ++w) pRow[w] = pr[w];
        }
        __syncthreads();  // WdL + pL ready
        // stage2: acc[w] += sum_c Wd[s][o][c] * p[c][tp][w]
        #pragma unroll 8
        for (int c = 0; c < 64; ++c) {
            float wd = WdL[c * 64 + co];
            const float* pc = &pL[c * 112 + tp * 28];
            #pragma unroll
            for (int w = 0; w < 25; ++w) acc[w] += wd * pc[w];
        }
    }

    // RACE FIX (round 1): stage2 above reads pL across ALL c rows from other
    // waves; must not overwrite pL with yv until every wave is done reading.
    __syncthreads();

    // epilogue: bias, BN (eval), residual, relu
    const float sc  = gamma[co] * rsqrtf(1.f + 1e-5f);
    const float bt  = beta[co];
    const float bds = bd[co] + bd[64 + co] + bd[128 + co];
    float yv[25];
    #pragma unroll
    for (int w = 0; w < 25; ++w) {
        float val = sc * (acc[w] + bds) + bt + xr[w];
        yv[w] = val > 0.f ? val : 0.f;
    }
    float* yp = y1 + (size_t)((n * 64 + co) * 256 + t) * 25;
    #pragma unroll
    for (int w = 0; w < 25; ++w) yp[w] = yv[w];

    // partial sum over the block's 4 t-values -> atomic into meanT (sum over T)
    {
        float* pRow = &pL[co * 112 + tp * 28];
        #pragma unroll
        for (int w = 0; w < 25; ++w) pRow[w] = yv[w];
    }
    __syncthreads();
    if (tp == 0) {
        #pragma unroll
        for (int w = 0; w < 25; ++w) {
            float sm = pL[co * 112 + w] + pL[co * 112 + 28 + w] +
                       pL[co * 112 + 56 + w] + pL[co * 112 + 84 + w];
            atomicAdd(&meanT[(n * 64 + co) * 25 + w], sm);
        }
    }
}

// ---------------------------------------------------------------------------
// Kernel D: spatial SE gate.  g2p[n][v] = 1 + sigmoid(conv_V(meanT/T, Wsa)+bsa)
// grid = N
// ---------------------------------------------------------------------------
__global__ __launch_bounds__(256) void gcn_kD(const float* __restrict__ meanT,
                                              const float* __restrict__ Wsa,
                                              const float* __restrict__ bsa,
                                              float* __restrict__ g2p) {
    const int n = blockIdx.x;
    const int tid = threadIdx.x;
    __shared__ float sm[1600], wl[1600];
    for (int j = tid; j < 1600; j += 256) {
        sm[j] = meanT[n * 1600 + j] * (1.f / 256.f);
        wl[j] = Wsa[j];
    }
    __syncthreads();
    if (tid < 25) {
        float acc = bsa[0];
        for (int c = 0; c < 64; ++c) {
            #pragma unroll
            for (int k = 0; k < 25; ++k) {
                int j = tid + k - 12;
                if (j >= 0 && j < 25) acc += sm[c * 25 + j] * wl[c * 25 + k];
            }
        }
        g2p[n * 25 + tid] = 1.f + 1.f / (1.f + expf(-acc));
    }
}

// ---------------------------------------------------------------------------
// Kernel E: M2[n][c][t] = (1/V) sum_v y1 * g2p[n][v]   (mean over V of y2)
// grid = N*C blocks, 256 threads = T
// ---------------------------------------------------------------------------
__global__ __launch_bounds__(256) void gcn_kE(const float* __restrict__ y1,
                                              const float* __restrict__ g2p,
                                              float* __restrict__ M2) {
    const int bid = blockIdx.x;     // n*64 + c
    const int n = bid >> 6;
    const int tid = threadIdx.x;
    __shared__ float yl[6400];
    __shared__ float g2l[25];
    const float* yp = y1 + (size_t)bid * 6400;
    for (int j = tid; j < 6400; j += 256) yl[j] = yp[j];
    if (tid < 25) g2l[tid] = g2p[n * 25 + tid];
    __syncthreads();
    float sum = 0.f;
    #pragma unroll
    for (int v = 0; v < 25; ++v) sum += yl[tid * 25 + v] * g2l[v];
    M2[bid * 256 + tid] = sum * 0.04f;   // 1/25
}

// ---------------------------------------------------------------------------
// Kernel F: temporal SE gate. g3p[n][t] = 1 + sigmoid(conv_T(M2, Wta)+bta)
// grid = N, 256 threads = T
// ---------------------------------------------------------------------------
__global__ __launch_bounds__(256) void gcn_kF(const float* __restrict__ M2,
                                              const float* __restrict__ Wta,
                                              const float* __restrict__ bta,
                                              float* __restrict__ g3p) {
    const int n = blockIdx.x;
    const int t = threadIdx.x;
    __shared__ float wl[576];
    for (int j = t; j < 576; j += 256) wl[j] = Wta[j];
    __syncthreads();
    float acc = bta[0];
    for (int c = 0; c < 64; ++c) {
        const float* mp = M2 + (size_t)(n * 64 + c) * 256;
        #pragma unroll
        for (int k = 0; k < 9; ++k) {
            int j = t + k - 4;
            if (j >= 0 && j < 256) acc += mp[j] * wl[c * 9 + k];
        }
    }
    g3p[n * 256 + t] = 1.f + 1.f / (1.f + expf(-acc));
}

// ---------------------------------------------------------------------------
// Kernel G: channel SE gate.
// M3[n][c] = (1/T) sum_t M2[n][c][t]*g3p[n][t]; MLP -> g4p[n][c] = 1+sigmoid
// grid = N
// ---------------------------------------------------------------------------
__global__ __launch_bounds__(256) void gcn_kG(const float* __restrict__ M2,
                                              const float* __restrict__ g3p,
                                              const float* __restrict__ W1,
                                              const float* __restrict__ b1,
                                              const float* __restrict__ W2,
                                              const float* __restrict__ b2,
                                              float* __restrict__ g4p) {
    const int n = blockIdx.x;
    const int tid = threadIdx.x;
    __shared__ float g3l[256], part[256], M3[64], h[32];
    g3l[tid] = g3p[n * 256 + tid];
    __syncthreads();
    const int c = tid >> 2, q = tid & 3;
    float p = 0.f;
    const float* mp = M2 + (size_t)(n * 64 + c) * 256 + q * 64;
    #pragma unroll 16
    for (int j = 0; j < 64; ++j) p += mp[j] * g3l[q * 64 + j];
    part[tid] = p;
    __syncthreads();
    if (tid < 64)
        M3[tid] = (part[tid * 4] + part[tid * 4 + 1] + part[tid * 4 + 2] +
                   part[tid * 4 + 3]) * (1.f / 256.f);
    __syncthreads();
    if (tid < 32) {
        float acc = b1[tid];
        #pragma unroll 16
        for (int cc = 0; cc < 64; ++cc) acc += W1[tid * 64 + cc] * M3[cc];
        h[tid] = acc > 0.f ? acc : 0.f;
    }
    __syncthreads();
    if (tid < 64) {
        float acc = b2[tid];
        #pragma unroll
        for (int j = 0; j < 32; ++j) acc += W2[tid * 32 + j] * h[j];
        g4p[n * 64 + tid] = 1.f + 1.f / (1.f + expf(-acc));
    }
}

// ---------------------------------------------------------------------------
// Kernel H: final gating, in place:  y = y1 * g2p[v] * g3p[t] * g4p[c]
// grid = N*C blocks
// ---------------------------------------------------------------------------
__global__ __launch_bounds__(256) void gcn_kH(float* __restrict__ y,
                                              const float* __restrict__ g2p,
                                              const float* __restrict__ g3p,
                                              const float* __restrict__ g4p) {
    const int bid = blockIdx.x;  // n*64 + c
    const int n = bid >> 6;
    const int tid = threadIdx.x;
    __shared__ float g3l[256], g2l[25];
    g3l[tid] = g3p[n * 256 + tid];
    if (tid < 25) g2l[tid] = g2p[n * 25 + tid];
    const float g4 = g4p[bid];
    __syncthreads();
    float4* yp = (float4*)(y + (size_t)bid * 6400);
    for (int f = tid; f < 1600; f += 256) {
        float4 val = yp[f];
        float* vv = (float*)&val;
        const int base = f * 4;
        #pragma unroll
        for (int k = 0; k < 4; ++k) {
            int idx = base + k;
            int t = (int)(((unsigned long long)idx * 1374389535ull) >> 35); // /25
            int v = idx - t * 25;
            vv[k] *= g2l[v] * g3l[t] * g4;
        }
        yp[f] = val;
    }
}

// ---------------------------------------------------------------------------
extern "C" void kernel_launch(void* const* d_in, const int* in_sizes, int n_in,
                              void* d_out, int out_size, void* d_ws, size_t ws_size,
                              hipStream_t stream) {
    const float* x     = (const float*)d_in[0];
    const float* PA    = (const float*)d_in[1];
    const float* alpha = (const float*)d_in[2];
    const float* Wa    = (const float*)d_in[3];
    const float* ba    = (const float*)d_in[4];
    const float* Wb    = (const float*)d_in[5];
    const float* bb    = (const float*)d_in[6];
    const float* Wd    = (const float*)d_in[7];
    const float* bd    = (const float*)d_in[8];
    const float* gamma = (const float*)d_in[9];
    const float* beta  = (const float*)d_in[10];
    const float* Wsa   = (const float*)d_in[11];
    const float* bsa   = (const float*)d_in[12];
    const float* Wta   = (const float*)d_in[13];
    const float* bta   = (const float*)d_in[14];
    const float* W1    = (const float*)d_in[15];
    const float* b1    = (const float*)d_in[16];
    const float* W2    = (const float*)d_in[17];
    const float* b2    = (const float*)d_in[18];

    float* out = (float*)d_out;
    float* ws  = (float*)d_ws;

    // workspace layout (floats)
    float* Praw  = ws;              // 120000  (zeroed)
    float* Ai    = ws + 120000;     // 120000
    float* WdT   = ws + 240000;     // 12288
    float* meanT = ws + 252288;     // 102400  (zeroed)
    float* g2p   = ws + 354688;     // 1600
    float* M2    = ws + 356288;     // 4194304
    float* g3p   = ws + 4550592;    // 16384
    float* g4p   = ws + 4566976;    // 4096    -> total 4,571,072 fl = 18.3 MB

    hipMemsetAsync(Praw, 0, 120000 * sizeof(float), stream);
    hipMemsetAsync(meanT, 0, 102400 * sizeof(float), stream);

    gcn_kA<<<768, 256, 0, stream>>>(x, Wa, ba, Wb, bb, Praw);
    gcn_kB<<<469, 256, 0, stream>>>(Praw, PA, alpha, Ai);
    gcn_kT<<<48, 256, 0, stream>>>(Wd, WdT);
    gcn_kC<<<4096, 256, 0, stream>>>(x, Ai, WdT, bd, gamma, beta, out, meanT);
    gcn_kD<<<64, 256, 0, stream>>>(meanT, Wsa, bsa, g2p);
    gcn_kE<<<4096, 256, 0, stream>>>(out, g2p, M2);
    gcn_kF<<<64, 256, 0, stream>>>(M2, Wta, bta, g3p);
    gcn_kG<<<64, 256, 0, stream>>>(M2, g3p, W1, b1, W2, b2, g4p);
    gcn_kH<<<4096, 256, 0, stream>>>(out, g2p, g3p, g4p);
}

// Round 3
// 892.172 us; speedup vs baseline: 1.4456x; 1.4456x over previous
//
#include <hip/hip_runtime.h>
#include <math.h>

// Problem constants
// N=64, C=64 (=Cout), T=256, V=25, S=3, inter=16
// x: [N,C,T,V] fp32;  out: [N,C,T,V] fp32

typedef __attribute__((ext_vector_type(8))) __bf16 bf16x8;
typedef __attribute__((ext_vector_type(4))) float  f32x4;

// ---------------------------------------------------------------------------
// Kernel A: fused embeddings + A1 Gram accumulation.  (unchanged from R1)
// grid = (s, n, tc) = 3*64*4 = 768 blocks, 256 threads.
// ---------------------------------------------------------------------------
__global__ __launch_bounds__(256) void gcn_kA(const float* __restrict__ x,
                                              const float* __restrict__ Wa,
                                              const float* __restrict__ ba,
                                              const float* __restrict__ Wb,
                                              const float* __restrict__ bb,
                                              float* __restrict__ Praw) {
    const int bid = blockIdx.x;
    const int tc = bid & 3;
    const int n  = (bid >> 2) & 63;
    const int s  = bid >> 8;
    const int tid = threadIdx.x;

    __shared__ float xs[6400];
    __shared__ float aL[1600], bL[1600];
    __shared__ float WaL[1024], WbL[1024];
    __shared__ float baL[16], bbL[16];

    for (int j = tid; j < 1024; j += 256) {
        WaL[j] = Wa[s * 1024 + j];
        WbL[j] = Wb[s * 1024 + j];
    }
    if (tid < 16) { baL[tid] = ba[s * 16 + tid]; bbL[tid] = bb[s * 16 + tid]; }

    float P0 = 0.f, P1 = 0.f, P2 = 0.f;
    const int p0 = tid, p1 = tid + 256, p2 = tid + 512;
    const int v0 = (int)(((unsigned long long)p0 * 1374389535ull) >> 35);
    const int w0 = p0 - v0 * 25;
    const int v1 = (int)(((unsigned long long)p1 * 1374389535ull) >> 35);
    const int w1 = p1 - v1 * 25;
    const int v2 = (int)(((unsigned long long)p2 * 1374389535ull) >> 35);
    const int w2 = p2 - v2 * 25;

    const int t0base = tc * 64;
    for (int tg = 0; tg < 16; ++tg) {
        const int t0 = t0base + tg * 4;
        __syncthreads();
        for (int j = tid; j < 6400; j += 256) {
            int c = (int)(((unsigned long long)j * 1374389535ull) >> 37);
            int r = j - c * 100;
            xs[j] = x[((n * 64 + c) * 256 + t0) * 25 + r];
        }
        __syncthreads();
        for (int e = tid; e < 1600; e += 256) {
            int i = (int)(((unsigned long long)e * 1374389535ull) >> 37);
            int r = e - i * 100;
            float av = baL[i], bv = bbL[i];
            #pragma unroll 16
            for (int c = 0; c < 64; ++c) {
                float xv = xs[c * 100 + r];
                av += WaL[i * 64 + c] * xv;
                bv += WbL[i * 64 + c] * xv;
            }
            aL[e] = av; bL[e] = bv;
        }
        __syncthreads();
        if (p0 < 625) {
            float acc = 0.f;
            #pragma unroll 16
            for (int m = 0; m < 64; ++m) acc += aL[m * 25 + v0] * bL[m * 25 + w0];
            P0 += acc;
        }
        if (p1 < 625) {
            float acc = 0.f;
            #pragma unroll 16
            for (int m = 0; m < 64; ++m) acc += aL[m * 25 + v1] * bL[m * 25 + w1];
            P1 += acc;
        }
        if (p2 < 625) {
            float acc = 0.f;
            #pragma unroll 16
            for (int m = 0; m < 64; ++m) acc += aL[m * 25 + v2] * bL[m * 25 + w2];
            P2 += acc;
        }
    }
    float* Pbase = Praw + (s * 64 + n) * 625;
    if (p0 < 625) atomicAdd(&Pbase[p0], P0);
    if (p1 < 625) atomicAdd(&Pbase[p1], P1);
    if (p2 < 625) atomicAdd(&Pbase[p2], P2);
}

// ---------------------------------------------------------------------------
// Kernel B: Ai = PA + alpha * tanh(P/4096).  120,000 elements.
// ---------------------------------------------------------------------------
__global__ __launch_bounds__(256) void gcn_kB(const float* __restrict__ Praw,
                                              const float* __restrict__ PA,
                                              const float* __restrict__ alpha,
                                              float* __restrict__ Ai) {
    int idx = blockIdx.x * 256 + threadIdx.x;
    if (idx >= 120000) return;
    int sn = idx / 625;
    int r  = idx - sn * 625;
    int s  = sn >> 6;
    Ai[idx] = PA[s * 625 + r] + alpha[0] * tanhf(Praw[idx] * (1.f / 4096.f));
}

// ---------------------------------------------------------------------------
// Kernel C (R2 rewrite, MFMA): commuted order
//   u_s = Wd[s] @ x[n]   (MFMA bf16 16x16x32: M=64 o, K=64 c, N=400 q=(t,v))
//   y[o,t,w] = relu(BN(sum_s sum_v u_s[o,t,v]*Ai[s,n,v,w]) + x[n,o,t,w])
// grid = 1024 blocks (n*16 + tt), 256 threads = 4 waves.
// Wave w owns M-tile (o = 16w..16w+15).  s-loop outer; u for one s lives in
// LDS bf16 (uL).  Stage-B (v-contraction) is per-thread VALU fp32.
// Also accumulates sum-over-T of y1 into meanT[n][c][v] (atomics).
// ---------------------------------------------------------------------------
__global__ __launch_bounds__(256) void gcn_kC(const float* __restrict__ x,
                                              const float* __restrict__ Ai,
                                              const float* __restrict__ Wd,
                                              const float* __restrict__ bd,
                                              const float* __restrict__ gamma,
                                              const float* __restrict__ beta,
                                              float* __restrict__ y1,
                                              float* __restrict__ meanT) {
    const int bid = blockIdx.x;
    const int tt = bid & 15;
    const int n  = bid >> 4;
    const int tid  = threadIdx.x;
    const int lane = tid & 63;
    const int wv   = tid >> 6;        // wave id = M-tile id
    const int m    = lane & 15;       // MFMA 16-col index
    const int quad = lane >> 4;
    const int o  = tid >> 2;          // stage-B channel (wave wv: o in [16wv,16wv+16))
    const int tp = tid & 3;
    const int t0 = tt * 16;

    __shared__ float AiL[1875];                      // [s][v*25+w]
    __shared__ __align__(16) __bf16 xB[80 * 72];     // [qs][c], stride 72
    __shared__ __align__(16) __bf16 uL[64 * 404];    // [o][lq], stride 404

    // stage Ai for this n (3 segments of 625, coalesced)
    for (int j = tid; j < 1875; j += 256) {
        int sj = j / 625;
        int r  = j - sj * 625;
        AiL[j] = Ai[(sj * 64 + n) * 625 + r];
    }

    float yacc[4][25];
    #pragma unroll
    for (int ti = 0; ti < 4; ++ti)
        #pragma unroll
        for (int w = 0; w < 25; ++w) yacc[ti][w] = 0.f;

    const float* xsrc = x + (size_t)n * 409600 + t0 * 25;  // + c*6400 + lq

    for (int s = 0; s < 3; ++s) {
        // A-frags: Wd[s][o][c], lane holds A[m=o_local][k=c=quad*8+j]
        bf16x8 a0, a1;
        {
            const float* wdp = Wd + (size_t)(s * 64 + wv * 16 + m) * 64 + quad * 8;
            #pragma unroll
            for (int j = 0; j < 8; ++j) a0[j] = (__bf16)wdp[j];
            #pragma unroll
            for (int j = 0; j < 8; ++j) a1[j] = (__bf16)wdp[32 + j];
        }

        for (int chunk = 0; chunk < 5; ++chunk) {
            __syncthreads();   // xB consumed by all waves (prev chunk / prev s)
            // stage xB[qs][c] bf16, qs = 0..79 (local q = chunk*80+qs)
            for (int j = tid; j < 5120; j += 256) {
                int c  = (int)(((unsigned)j * 13108u) >> 20);  // j/80
                int qs = j - c * 80;
                xB[qs * 72 + c] = (__bf16)xsrc[c * 6400 + chunk * 80 + qs];
            }
            __syncthreads();
            #pragma unroll
            for (int jt = 0; jt < 5; ++jt) {
                const __bf16* bp = &xB[(jt * 16 + m) * 72 + quad * 8];
                bf16x8 b0 = *(const bf16x8*)bp;
                bf16x8 b1 = *(const bf16x8*)(bp + 32);
                f32x4 acc = {0.f, 0.f, 0.f, 0.f};
                acc = __builtin_amdgcn_mfma_f32_16x16x32_bf16(a0, b0, acc, 0, 0, 0);
                acc = __builtin_amdgcn_mfma_f32_16x16x32_bf16(a1, b1, acc, 0, 0, 0);
                int qg = (chunk * 5 + jt) * 16 + m;            // local q in [0,400)
                int orow = (wv * 16 + quad * 4) * 404 + qg;
                uL[orow]           = (__bf16)acc[0];
                uL[orow + 404]     = (__bf16)acc[1];
                uL[orow + 2 * 404] = (__bf16)acc[2];
                uL[orow + 3 * 404] = (__bf16)acc[3];
            }
        }
        // stage-B: y[o, t=tp+4*ti, w] += sum_v u[o, t*25+v] * Ai[s][v][w]
        // (wave reads only its own uL rows; in-wave DS ordering suffices)
        const float* AiS = AiL + s * 625;
        const __bf16* up = uL + o * 404;
        for (int v = 0; v < 25; ++v) {
            float uv0 = (float)up[tp * 25 + v];
            float uv1 = (float)up[(tp + 4) * 25 + v];
            float uv2 = (float)up[(tp + 8) * 25 + v];
            float uv3 = (float)up[(tp + 12) * 25 + v];
            const float* ai = AiS + v * 25;
            #pragma unroll
            for (int w = 0; w < 25; ++w) {
                float a = ai[w];
                yacc[0][w] += uv0 * a;
                yacc[1][w] += uv1 * a;
                yacc[2][w] += uv2 * a;
                yacc[3][w] += uv3 * a;
            }
        }
    }

    // epilogue: bias, BN (eval), residual, relu, store, meanT partials
    const float sc  = gamma[o] * rsqrtf(1.f + 1e-5f);
    const float bt  = beta[o];
    const float bds = bd[o] + bd[64 + o] + bd[128 + o];
    float msum[25];
    #pragma unroll
    for (int w = 0; w < 25; ++w) msum[w] = 0.f;
    #pragma unroll
    for (int ti = 0; ti < 4; ++ti) {
        int t = t0 + tp + ti * 4;
        const float* xp = x + ((size_t)(n * 64 + o) * 256 + t) * 25;
        float* yp = y1 + ((size_t)(n * 64 + o) * 256 + t) * 25;
        #pragma unroll
        for (int w = 0; w < 25; ++w) {
            float val = sc * (yacc[ti][w] + bds) + bt + xp[w];
            val = val > 0.f ? val : 0.f;
            yp[w] = val;
            msum[w] += val;
        }
    }
    // reduce msum over tp (4 lanes per o) via uL scratch (own rows only)
    float* mt = (float*)(uL + o * 404);   // 202 floats available per o-row
    #pragma unroll
    for (int w = 0; w < 25; ++w) mt[tp * 25 + w] = msum[w];
    __syncthreads();
    if (tp == 0) {
        #pragma unroll
        for (int w = 0; w < 25; ++w) {
            float sm = mt[w] + mt[25 + w] + mt[50 + w] + mt[75 + w];
            atomicAdd(&meanT[(n * 64 + o) * 25 + w], sm);
        }
    }
}

// ---------------------------------------------------------------------------
// Kernel D: spatial SE gate.  g2p[n][v] = 1 + sigmoid(conv_V(meanT/T, Wsa)+bsa)
// ---------------------------------------------------------------------------
__global__ __launch_bounds__(256) void gcn_kD(const float* __restrict__ meanT,
                                              const float* __restrict__ Wsa,
                                              const float* __restrict__ bsa,
                                              float* __restrict__ g2p) {
    const int n = blockIdx.x;
    const int tid = threadIdx.x;
    __shared__ float sm[1600], wl[1600];
    for (int j = tid; j < 1600; j += 256) {
        sm[j] = meanT[n * 1600 + j] * (1.f / 256.f);
        wl[j] = Wsa[j];
    }
    __syncthreads();
    if (tid < 25) {
        float acc = bsa[0];
        for (int c = 0; c < 64; ++c) {
            #pragma unroll
            for (int k = 0; k < 25; ++k) {
                int j = tid + k - 12;
                if (j >= 0 && j < 25) acc += sm[c * 25 + j] * wl[c * 25 + k];
            }
        }
        g2p[n * 25 + tid] = 1.f + 1.f / (1.f + expf(-acc));
    }
}

// ---------------------------------------------------------------------------
// Kernel E: M2[n][c][t] = (1/V) sum_v y1 * g2p[n][v]
// ---------------------------------------------------------------------------
__global__ __launch_bounds__(256) void gcn_kE(const float* __restrict__ y1,
                                              const float* __restrict__ g2p,
                                              float* __restrict__ M2) {
    const int bid = blockIdx.x;     // n*64 + c
    const int n = bid >> 6;
    const int tid = threadIdx.x;
    __shared__ float yl[6400];
    __shared__ float g2l[25];
    const float* yp = y1 + (size_t)bid * 6400;
    for (int j = tid; j < 6400; j += 256) yl[j] = yp[j];
    if (tid < 25) g2l[tid] = g2p[n * 25 + tid];
    __syncthreads();
    float sum = 0.f;
    #pragma unroll
    for (int v = 0; v < 25; ++v) sum += yl[tid * 25 + v] * g2l[v];
    M2[bid * 256 + tid] = sum * 0.04f;
}

// ---------------------------------------------------------------------------
// Kernel F: temporal SE gate. g3p[n][t] = 1 + sigmoid(conv_T(M2, Wta)+bta)
// ---------------------------------------------------------------------------
__global__ __launch_bounds__(256) void gcn_kF(const float* __restrict__ M2,
                                              const float* __restrict__ Wta,
                                              const float* __restrict__ bta,
                                              float* __restrict__ g3p) {
    const int n = blockIdx.x;
    const int t = threadIdx.x;
    __shared__ float wl[576];
    for (int j = t; j < 576; j += 256) wl[j] = Wta[j];
    __syncthreads();
    float acc = bta[0];
    for (int c = 0; c < 64; ++c) {
        const float* mp = M2 + (size_t)(n * 64 + c) * 256;
        #pragma unroll
        for (int k = 0; k < 9; ++k) {
            int j = t + k - 4;
            if (j >= 0 && j < 256) acc += mp[j] * wl[c * 9 + k];
        }
    }
    g3p[n * 256 + t] = 1.f + 1.f / (1.f + expf(-acc));
}

// ---------------------------------------------------------------------------
// Kernel G: channel SE gate.
// ---------------------------------------------------------------------------
__global__ __launch_bounds__(256) void gcn_kG(const float* __restrict__ M2,
                                              const float* __restrict__ g3p,
                                              const float* __restrict__ W1,
                                              const float* __restrict__ b1,
                                              const float* __restrict__ W2,
                                              const float* __restrict__ b2,
                                              float* __restrict__ g4p) {
    const int n = blockIdx.x;
    const int tid = threadIdx.x;
    __shared__ float g3l[256], part[256], M3[64], h[32];
    g3l[tid] = g3p[n * 256 + tid];
    __syncthreads();
    const int c = tid >> 2, q = tid & 3;
    float p = 0.f;
    const float* mp = M2 + (size_t)(n * 64 + c) * 256 + q * 64;
    #pragma unroll 16
    for (int j = 0; j < 64; ++j) p += mp[j] * g3l[q * 64 + j];
    part[tid] = p;
    __syncthreads();
    if (tid < 64)
        M3[tid] = (part[tid * 4] + part[tid * 4 + 1] + part[tid * 4 + 2] +
                   part[tid * 4 + 3]) * (1.f / 256.f);
    __syncthreads();
    if (tid < 32) {
        float acc = b1[tid];
        #pragma unroll 16
        for (int cc = 0; cc < 64; ++cc) acc += W1[tid * 64 + cc] * M3[cc];
        h[tid] = acc > 0.f ? acc : 0.f;
    }
    __syncthreads();
    if (tid < 64) {
        float acc = b2[tid];
        #pragma unroll
        for (int j = 0; j < 32; ++j) acc += W2[tid * 32 + j] * h[j];
        g4p[n * 64 + tid] = 1.f + 1.f / (1.f + expf(-acc));
    }
}

// ---------------------------------------------------------------------------
// Kernel H: final gating, in place:  y = y1 * g2p[v] * g3p[t] * g4p[c]
// ---------------------------------------------------------------------------
__global__ __launch_bounds__(256) void gcn_kH(float* __restrict__ y,
                                              const float* __restrict__ g2p,
                                              const float* __restrict__ g3p,
                                              const float* __restrict__ g4p) {
    const int bid = blockIdx.x;  // n*64 + c
    const int n = bid >> 6;
    const int tid = threadIdx.x;
    __shared__ float g3l[256], g2l[25];
    g3l[tid] = g3p[n * 256 + tid];
    if (tid < 25) g2l[tid] = g2p[n * 25 + tid];
    const float g4 = g4p[bid];
    __syncthreads();
    float4* yp = (float4*)(y + (size_t)bid * 6400);
    for (int f = tid; f < 1600; f += 256) {
        float4 val = yp[f];
        float* vv = (float*)&val;
        const int base = f * 4;
        #pragma unroll
        for (int k = 0; k < 4; ++k) {
            int idx = base + k;
            int t = (int)(((unsigned long long)idx * 1374389535ull) >> 35);
            int v = idx - t * 25;
            vv[k] *= g2l[v] * g3l[t] * g4;
        }
        yp[f] = val;
    }
}

// ---------------------------------------------------------------------------
extern "C" void kernel_launch(void* const* d_in, const int* in_sizes, int n_in,
                              void* d_out, int out_size, void* d_ws, size_t ws_size,
                              hipStream_t stream) {
    const float* x     = (const float*)d_in[0];
    const float* PA    = (const float*)d_in[1];
    const float* alpha = (const float*)d_in[2];
    const float* Wa    = (const float*)d_in[3];
    const float* ba    = (const float*)d_in[4];
    const float* Wb    = (const float*)d_in[5];
    const float* bb    = (const float*)d_in[6];
    const float* Wd    = (const float*)d_in[7];
    const float* bd    = (const float*)d_in[8];
    const float* gamma = (const float*)d_in[9];
    const float* beta  = (const float*)d_in[10];
    const float* Wsa   = (const float*)d_in[11];
    const float* bsa   = (const float*)d_in[12];
    const float* Wta   = (const float*)d_in[13];
    const float* bta   = (const float*)d_in[14];
    const float* W1    = (const float*)d_in[15];
    const float* b1    = (const float*)d_in[16];
    const float* W2    = (const float*)d_in[17];
    const float* b2    = (const float*)d_in[18];

    float* out = (float*)d_out;
    float* ws  = (float*)d_ws;

    // workspace layout (floats)
    float* Praw  = ws;              // 120000  (zeroed)
    float* Ai    = ws + 120000;     // 120000
    float* meanT = ws + 252288;     // 102400  (zeroed)
    float* g2p   = ws + 354688;     // 1600
    float* M2    = ws + 356288;     // 4194304
    float* g3p   = ws + 4550592;    // 16384
    float* g4p   = ws + 4566976;    // 4096

    hipMemsetAsync(Praw, 0, 120000 * sizeof(float), stream);
    hipMemsetAsync(meanT, 0, 102400 * sizeof(float), stream);

    gcn_kA<<<768, 256, 0, stream>>>(x, Wa, ba, Wb, bb, Praw);
    gcn_kB<<<469, 256, 0, stream>>>(Praw, PA, alpha, Ai);
    gcn_kC<<<1024, 256, 0, stream>>>(x, Ai, Wd, bd, gamma, beta, out, meanT);
    gcn_kD<<<64, 256, 0, stream>>>(meanT, Wsa, bsa, g2p);
    gcn_kE<<<4096, 256, 0, stream>>>(out, g2p, M2);
    gcn_kF<<<64, 256, 0, stream>>>(M2, Wta, bta, g3p);
    gcn_kG<<<64, 256, 0, stream>>>(M2, g3p, W1, b1, W2, b2, g4p);
    gcn_kH<<<4096, 256, 0, stream>>>(out, g2p, g3p, g4p);
}

// Round 4
// 813.208 us; speedup vs baseline: 1.5860x; 1.0971x over previous
//
#include <hip/hip_runtime.h>
#include <math.h>

// Problem constants
// N=64, C=64 (=Cout), T=256, V=25, S=3, inter=16
// x: [N,C,T,V] fp32;  out: [N,C,T,V] fp32

typedef __attribute__((ext_vector_type(8))) __bf16 bf16x8;
typedef __attribute__((ext_vector_type(4))) float  f32x4;

// ---------------------------------------------------------------------------
// Kernel A (R4 rewrite, full MFMA): per (s,n) block computes
//   a = Wa[s]@x[n]+ba, b = Wb[s]@x[n]+bb        (MFMA, M=16 i, K=64 c, N=6400 q)
//   P[v][w] = sum_{i,t} a[i,t,v]*b[i,t,w]       (MFMA, M=25, N=25, K=4096)
//   Ai[s,n] = PA[s] + alpha*tanh(P/4096)        (epilogue; kB folded in)
// grid = 192 blocks (s*64+n), 256 threads = 4 waves.
// Wave wv owns Gram output tile (mi=wv>>1, ni=wv&1); P accumulates in AGPRs
// across 16 t-chunks (Tc=16 -> 400 q-columns, K-chunk = 16i*16t = 256).
// ---------------------------------------------------------------------------
__global__ __launch_bounds__(256) void gcn_kA(const float* __restrict__ x,
                                              const float* __restrict__ Wa,
                                              const float* __restrict__ ba,
                                              const float* __restrict__ Wb,
                                              const float* __restrict__ bb,
                                              const float* __restrict__ PA,
                                              const float* __restrict__ alpha,
                                              float* __restrict__ Ai) {
    const int bid = blockIdx.x;      // s*64 + n
    const int s = bid >> 6;
    const int n = bid & 63;
    const int tid  = threadIdx.x;
    const int lane = tid & 63;
    const int wv   = tid >> 6;
    const int col  = lane & 15;
    const int quad = lane >> 4;

    const int BQ = 412;              // xB row stride (bf16); 8-mult for b64 align
    const int KS = 264;              // aT/bT row stride (bf16); 16B-aligned rows
    __shared__ __align__(16) __bf16 xB[64 * 412];   // [c][q]   52,736 B
    __shared__ __align__(16) __bf16 aT[32 * 264];   // [v][k]   16,896 B
    __shared__ __align__(16) __bf16 bT[32 * 264];   // [v][k]   16,896 B

    // A-fragments (regs): A[m=i=col][k=c=kh*32+quad*8+j]
    bf16x8 wa0, wa1, wb0, wb1;
    {
        const float* wap = Wa + (size_t)s * 1024 + col * 64 + quad * 8;
        const float* wbp = Wb + (size_t)s * 1024 + col * 64 + quad * 8;
        #pragma unroll
        for (int j = 0; j < 8; ++j) { wa0[j] = (__bf16)wap[j];      wb0[j] = (__bf16)wbp[j]; }
        #pragma unroll
        for (int j = 0; j < 8; ++j) { wa1[j] = (__bf16)wap[32 + j]; wb1[j] = (__bf16)wbp[32 + j]; }
    }
    float ba4[4], bb4[4];
    #pragma unroll
    for (int r = 0; r < 4; ++r) {
        ba4[r] = ba[s * 16 + quad * 4 + r];
        bb4[r] = bb[s * 16 + quad * 4 + r];
    }

    // zero aT/bT pad rows 25..31 (read by Gram tiles mi=1/ni=1, results discarded)
    for (int j = tid; j < 7 * KS; j += 256) {
        aT[25 * KS + j] = (__bf16)0.f;
        bT[25 * KS + j] = (__bf16)0.f;
    }

    f32x4 pacc = {0.f, 0.f, 0.f, 0.f};
    const int mi = wv >> 1, ni = wv & 1;

    const float* xn = x + (size_t)n * 409600;
    for (int ch = 0; ch < 16; ++ch) {
        __syncthreads();   // prev Gram done with aT/bT; prev embed done with xB
        // stage xB[c][q] = bf16(x[n][c][ch*400 + q]), q in [0,400)
        #pragma unroll
        for (int it = 0; it < 25; ++it) {
            int j4 = tid + it * 256;                 // < 6400
            int c  = j4 / 100;
            int qq = (j4 - c * 100) * 4;
            float4 xv = *(const float4*)(xn + c * 6400 + ch * 400 + qq);
            __bf16* dst = &xB[c * BQ + qq];
            dst[0] = (__bf16)xv.x; dst[1] = (__bf16)xv.y;
            dst[2] = (__bf16)xv.z; dst[3] = (__bf16)xv.w;
        }
        __syncthreads();
        // embedding MFMA: q-tiles of 16; wave wv takes jt = wv, wv+4, ...
        for (int jt = wv; jt < 25; jt += 4) {
            int q = jt * 16 + col;
            bf16x8 b0, b1;                           // B[k=c][n=q] = xB[c][q]
            #pragma unroll
            for (int j = 0; j < 8; ++j) b0[j] = xB[(quad * 8 + j) * BQ + q];
            #pragma unroll
            for (int j = 0; j < 8; ++j) b1[j] = xB[(32 + quad * 8 + j) * BQ + q];
            f32x4 da = {0.f, 0.f, 0.f, 0.f}, db = {0.f, 0.f, 0.f, 0.f};
            da = __builtin_amdgcn_mfma_f32_16x16x32_bf16(wa0, b0, da, 0, 0, 0);
            da = __builtin_amdgcn_mfma_f32_16x16x32_bf16(wa1, b1, da, 0, 0, 0);
            db = __builtin_amdgcn_mfma_f32_16x16x32_bf16(wb0, b0, db, 0, 0, 0);
            db = __builtin_amdgcn_mfma_f32_16x16x32_bf16(wb1, b1, db, 0, 0, 0);
            // D[row=i=quad*4+r][col=q]; scatter to aT/bT[v][k=i*16+tl]
            int v = q % 25, tl = q / 25;
            #pragma unroll
            for (int r = 0; r < 4; ++r) {
                int ko = (quad * 4 + r) * 16 + tl;
                aT[v * KS + ko] = (__bf16)(da[r] + ba4[r]);
                bT[v * KS + ko] = (__bf16)(db[r] + bb4[r]);
            }
        }
        __syncthreads();
        // Gram MFMA: K-chunk = 256; A[m=v][k] = aT row, B[k][n=w] = bT row w
        #pragma unroll
        for (int k0 = 0; k0 < 256; k0 += 32) {
            bf16x8 af = *(const bf16x8*)&aT[(mi * 16 + col) * KS + k0 + quad * 8];
            bf16x8 bf = *(const bf16x8*)&bT[(ni * 16 + col) * KS + k0 + quad * 8];
            pacc = __builtin_amdgcn_mfma_f32_16x16x32_bf16(af, bf, pacc, 0, 0, 0);
        }
    }

    // epilogue (kB folded in): Ai = PA + alpha*tanh(P/4096)
    const float al = alpha[0];
    #pragma unroll
    for (int r = 0; r < 4; ++r) {
        int v = mi * 16 + quad * 4 + r;   // D row
        int w = ni * 16 + col;            // D col
        if (v < 25 && w < 25)
            Ai[(s * 64 + n) * 625 + v * 25 + w] =
                PA[s * 625 + v * 25 + w] + al * tanhf(pacc[r] * (1.f / 4096.f));
    }
}

// ---------------------------------------------------------------------------
// Kernel C (unchanged from R3, MFMA): commuted order
//   u_s = Wd[s] @ x[n];  y = relu(BN(sum_s sum_v u_s*Ai) + x)
// grid = 1024 blocks (n*16 + tt), 256 threads = 4 waves.
// ---------------------------------------------------------------------------
__global__ __launch_bounds__(256) void gcn_kC(const float* __restrict__ x,
                                              const float* __restrict__ Ai,
                                              const float* __restrict__ Wd,
                                              const float* __restrict__ bd,
                                              const float* __restrict__ gamma,
                                              const float* __restrict__ beta,
                                              float* __restrict__ y1,
                                              float* __restrict__ meanT) {
    const int bid = blockIdx.x;
    const int tt = bid & 15;
    const int n  = bid >> 4;
    const int tid  = threadIdx.x;
    const int lane = tid & 63;
    const int wv   = tid >> 6;
    const int m    = lane & 15;
    const int quad = lane >> 4;
    const int o  = tid >> 2;
    const int tp = tid & 3;
    const int t0 = tt * 16;

    __shared__ float AiL[1875];
    __shared__ __align__(16) __bf16 xB[80 * 72];
    __shared__ __align__(16) __bf16 uL[64 * 404];

    for (int j = tid; j < 1875; j += 256) {
        int sj = j / 625;
        int r  = j - sj * 625;
        AiL[j] = Ai[(sj * 64 + n) * 625 + r];
    }

    float yacc[4][25];
    #pragma unroll
    for (int ti = 0; ti < 4; ++ti)
        #pragma unroll
        for (int w = 0; w < 25; ++w) yacc[ti][w] = 0.f;

    const float* xsrc = x + (size_t)n * 409600 + t0 * 25;

    for (int s = 0; s < 3; ++s) {
        bf16x8 a0, a1;
        {
            const float* wdp = Wd + (size_t)(s * 64 + wv * 16 + m) * 64 + quad * 8;
            #pragma unroll
            for (int j = 0; j < 8; ++j) a0[j] = (__bf16)wdp[j];
            #pragma unroll
            for (int j = 0; j < 8; ++j) a1[j] = (__bf16)wdp[32 + j];
        }

        for (int chunk = 0; chunk < 5; ++chunk) {
            __syncthreads();
            for (int j = tid; j < 5120; j += 256) {
                int c  = (int)(((unsigned)j * 13108u) >> 20);  // j/80
                int qs = j - c * 80;
                xB[qs * 72 + c] = (__bf16)xsrc[c * 6400 + chunk * 80 + qs];
            }
            __syncthreads();
            #pragma unroll
            for (int jt = 0; jt < 5; ++jt) {
                const __bf16* bp = &xB[(jt * 16 + m) * 72 + quad * 8];
                bf16x8 b0 = *(const bf16x8*)bp;
                bf16x8 b1 = *(const bf16x8*)(bp + 32);
                f32x4 acc = {0.f, 0.f, 0.f, 0.f};
                acc = __builtin_amdgcn_mfma_f32_16x16x32_bf16(a0, b0, acc, 0, 0, 0);
                acc = __builtin_amdgcn_mfma_f32_16x16x32_bf16(a1, b1, acc, 0, 0, 0);
                int qg = (chunk * 5 + jt) * 16 + m;
                int orow = (wv * 16 + quad * 4) * 404 + qg;
                uL[orow]           = (__bf16)acc[0];
                uL[orow + 404]     = (__bf16)acc[1];
                uL[orow + 2 * 404] = (__bf16)acc[2];
                uL[orow + 3 * 404] = (__bf16)acc[3];
            }
        }
        const float* AiS = AiL + s * 625;
        const __bf16* up = uL + o * 404;
        for (int v = 0; v < 25; ++v) {
            float uv0 = (float)up[tp * 25 + v];
            float uv1 = (float)up[(tp + 4) * 25 + v];
            float uv2 = (float)up[(tp + 8) * 25 + v];
            float uv3 = (float)up[(tp + 12) * 25 + v];
            const float* ai = AiS + v * 25;
            #pragma unroll
            for (int w = 0; w < 25; ++w) {
                float a = ai[w];
                yacc[0][w] += uv0 * a;
                yacc[1][w] += uv1 * a;
                yacc[2][w] += uv2 * a;
                yacc[3][w] += uv3 * a;
            }
        }
    }

    const float sc  = gamma[o] * rsqrtf(1.f + 1e-5f);
    const float bt  = beta[o];
    const float bds = bd[o] + bd[64 + o] + bd[128 + o];
    float msum[25];
    #pragma unroll
    for (int w = 0; w < 25; ++w) msum[w] = 0.f;
    #pragma unroll
    for (int ti = 0; ti < 4; ++ti) {
        int t = t0 + tp + ti * 4;
        const float* xp = x + ((size_t)(n * 64 + o) * 256 + t) * 25;
        float* yp = y1 + ((size_t)(n * 64 + o) * 256 + t) * 25;
        #pragma unroll
        for (int w = 0; w < 25; ++w) {
            float val = sc * (yacc[ti][w] + bds) + bt + xp[w];
            val = val > 0.f ? val : 0.f;
            yp[w] = val;
            msum[w] += val;
        }
    }
    float* mt = (float*)(uL + o * 404);
    #pragma unroll
    for (int w = 0; w < 25; ++w) mt[tp * 25 + w] = msum[w];
    __syncthreads();
    if (tp == 0) {
        #pragma unroll
        for (int w = 0; w < 25; ++w) {
            float sm = mt[w] + mt[25 + w] + mt[50 + w] + mt[75 + w];
            atomicAdd(&meanT[(n * 64 + o) * 25 + w], sm);
        }
    }
}

// ---------------------------------------------------------------------------
// Kernel D: spatial SE gate.  g2p[n][v] = 1 + sigmoid(conv_V(meanT/T, Wsa)+bsa)
// ---------------------------------------------------------------------------
__global__ __launch_bounds__(256) void gcn_kD(const float* __restrict__ meanT,
                                              const float* __restrict__ Wsa,
                                              const float* __restrict__ bsa,
                                              float* __restrict__ g2p) {
    const int n = blockIdx.x;
    const int tid = threadIdx.x;
    __shared__ float sm[1600], wl[1600];
    for (int j = tid; j < 1600; j += 256) {
        sm[j] = meanT[n * 1600 + j] * (1.f / 256.f);
        wl[j] = Wsa[j];
    }
    __syncthreads();
    if (tid < 25) {
        float acc = bsa[0];
        for (int c = 0; c < 64; ++c) {
            #pragma unroll
            for (int k = 0; k < 25; ++k) {
                int j = tid + k - 12;
                if (j >= 0 && j < 25) acc += sm[c * 25 + j] * wl[c * 25 + k];
            }
        }
        g2p[n * 25 + tid] = 1.f + 1.f / (1.f + expf(-acc));
    }
}

// ---------------------------------------------------------------------------
// Kernel E: M2[n][c][t] = (1/V) sum_v y1 * g2p[n][v]
// ---------------------------------------------------------------------------
__global__ __launch_bounds__(256) void gcn_kE(const float* __restrict__ y1,
                                              const float* __restrict__ g2p,
                                              float* __restrict__ M2) {
    const int bid = blockIdx.x;     // n*64 + c
    const int n = bid >> 6;
    const int tid = threadIdx.x;
    __shared__ float yl[6400];
    __shared__ float g2l[25];
    const float* yp = y1 + (size_t)bid * 6400;
    for (int j = tid; j < 6400; j += 256) yl[j] = yp[j];
    if (tid < 25) g2l[tid] = g2p[n * 25 + tid];
    __syncthreads();
    float sum = 0.f;
    #pragma unroll
    for (int v = 0; v < 25; ++v) sum += yl[tid * 25 + v] * g2l[v];
    M2[bid * 256 + tid] = sum * 0.04f;
}

// ---------------------------------------------------------------------------
// Kernel FG (R4 merge of kF+kG): per n, stage M2[n] in LDS once, then
//   g3[t] = 1 + sigmoid(conv_T(M2, Wta)+bta)
//   M3[c] = (1/T) sum_t M2[c][t]*g3[t];  MLP -> g4[c] = 1+sigmoid
// grid = N = 64 blocks.
// ---------------------------------------------------------------------------
__global__ __launch_bounds__(256) void gcn_kFG(const float* __restrict__ M2,
                                               const float* __restrict__ Wta,
                                               const float* __restrict__ bta,
                                               const float* __restrict__ W1,
                                               const float* __restrict__ b1,
                                               const float* __restrict__ W2,
                                               const float* __restrict__ b2,
                                               float* __restrict__ g3p,
                                               float* __restrict__ g4p) {
    const int n = blockIdx.x;
    const int tid = threadIdx.x;
    __shared__ float m2L[64 * 260];   // [c][t], pad 260
    __shared__ float wl[576];
    __shared__ float g3l[256], part[256], M3[64], h[32];

    for (int j = tid; j < 16384; j += 256) {
        int c = j >> 8, t = j & 255;
        m2L[c * 260 + t] = M2[(size_t)n * 16384 + j];
    }
    for (int j = tid; j < 576; j += 256) wl[j] = Wta[j];
    __syncthreads();

    // phase F: temporal conv (kernel 9, pad 4), t = tid
    {
        const int t = tid;
        float acc = bta[0];
        for (int c = 0; c < 64; ++c) {
            const float* mp = &m2L[c * 260];
            #pragma unroll
            for (int k = 0; k < 9; ++k) {
                int j = t + k - 4;
                if (j >= 0 && j < 256) acc += mp[j] * wl[c * 9 + k];
            }
        }
        float g3 = 1.f + 1.f / (1.f + expf(-acc));
        g3l[t] = g3;
        g3p[n * 256 + t] = g3;
    }
    __syncthreads();

    // phase G: channel SE
    {
        const int c = tid >> 2, q = tid & 3;
        float p = 0.f;
        const float* mp = &m2L[c * 260 + q * 64];
        #pragma unroll 16
        for (int j = 0; j < 64; ++j) p += mp[j] * g3l[q * 64 + j];
        part[tid] = p;
    }
    __syncthreads();
    if (tid < 64)
        M3[tid] = (part[tid * 4] + part[tid * 4 + 1] + part[tid * 4 + 2] +
                   part[tid * 4 + 3]) * (1.f / 256.f);
    __syncthreads();
    if (tid < 32) {
        float acc = b1[tid];
        #pragma unroll 16
        for (int cc = 0; cc < 64; ++cc) acc += W1[tid * 64 + cc] * M3[cc];
        h[tid] = acc > 0.f ? acc : 0.f;
    }
    __syncthreads();
    if (tid < 64) {
        float acc = b2[tid];
        #pragma unroll
        for (int j = 0; j < 32; ++j) acc += W2[tid * 32 + j] * h[j];
        g4p[n * 64 + tid] = 1.f + 1.f / (1.f + expf(-acc));
    }
}

// ---------------------------------------------------------------------------
// Kernel H: final gating, in place:  y = y1 * g2p[v] * g3p[t] * g4p[c]
// ---------------------------------------------------------------------------
__global__ __launch_bounds__(256) void gcn_kH(float* __restrict__ y,
                                              const float* __restrict__ g2p,
                                              const float* __restrict__ g3p,
                                              const float* __restrict__ g4p) {
    const int bid = blockIdx.x;  // n*64 + c
    const int n = bid >> 6;
    const int tid = threadIdx.x;
    __shared__ float g3l[256], g2l[25];
    g3l[tid] = g3p[n * 256 + tid];
    if (tid < 25) g2l[tid] = g2p[n * 25 + tid];
    const float g4 = g4p[bid];
    __syncthreads();
    float4* yp = (float4*)(y + (size_t)bid * 6400);
    for (int f = tid; f < 1600; f += 256) {
        float4 val = yp[f];
        float* vv = (float*)&val;
        const int base = f * 4;
        #pragma unroll
        for (int k = 0; k < 4; ++k) {
            int idx = base + k;
            int t = (int)(((unsigned long long)idx * 1374389535ull) >> 35);
            int v = idx - t * 25;
            vv[k] *= g2l[v] * g3l[t] * g4;
        }
        yp[f] = val;
    }
}

// ---------------------------------------------------------------------------
extern "C" void kernel_launch(void* const* d_in, const int* in_sizes, int n_in,
                              void* d_out, int out_size, void* d_ws, size_t ws_size,
                              hipStream_t stream) {
    const float* x     = (const float*)d_in[0];
    const float* PA    = (const float*)d_in[1];
    const float* alpha = (const float*)d_in[2];
    const float* Wa    = (const float*)d_in[3];
    const float* ba    = (const float*)d_in[4];
    const float* Wb    = (const float*)d_in[5];
    const float* bb    = (const float*)d_in[6];
    const float* Wd    = (const float*)d_in[7];
    const float* bd    = (const float*)d_in[8];
    const float* gamma = (const float*)d_in[9];
    const float* beta  = (const float*)d_in[10];
    const float* Wsa   = (const float*)d_in[11];
    const float* bsa   = (const float*)d_in[12];
    const float* Wta   = (const float*)d_in[13];
    const float* bta   = (const float*)d_in[14];
    const float* W1    = (const float*)d_in[15];
    const float* b1    = (const float*)d_in[16];
    const float* W2    = (const float*)d_in[17];
    const float* b2    = (const float*)d_in[18];

    float* out = (float*)d_out;
    float* ws  = (float*)d_ws;

    // workspace layout (floats)
    float* Ai    = ws + 120000;     // 120000
    float* meanT = ws + 252288;     // 102400  (zeroed; kC atomics)
    float* g2p   = ws + 354688;     // 1600
    float* M2    = ws + 356288;     // 4194304
    float* g3p   = ws + 4550592;    // 16384
    float* g4p   = ws + 4566976;    // 4096

    hipMemsetAsync(meanT, 0, 102400 * sizeof(float), stream);

    gcn_kA<<<192, 256, 0, stream>>>(x, Wa, ba, Wb, bb, PA, alpha, Ai);
    gcn_kC<<<1024, 256, 0, stream>>>(x, Ai, Wd, bd, gamma, beta, out, meanT);
    gcn_kD<<<64, 256, 0, stream>>>(meanT, Wsa, bsa, g2p);
    gcn_kE<<<4096, 256, 0, stream>>>(out, g2p, M2);
    gcn_kFG<<<64, 256, 0, stream>>>(M2, Wta, bta, W1, b1, W2, b2, g3p, g4p);
    gcn_kH<<<4096, 256, 0, stream>>>(out, g2p, g3p, g4p);
}